// Round 17
// baseline (66.279 us; speedup 1.0000x reference)
//
#include <hip/hip_runtime.h>
#include <hip/hip_bf16.h>
#include <math.h>

#define H_ 14
#define W_ 14
#define HW_ 196
#define CIN_ 1024
#define CMID_ 256
#define NCLS_ 27
#define NB_ 16
#define ROIS_ 980
#define M_ 3136
#define FEAT_ 2304
#define NROI_ (NB_ * ROIS_)   // 15680
#define NCB_ 256              // padded cb = cls*9+bin (243 real)

typedef unsigned short u16;
typedef __attribute__((ext_vector_type(8))) short bf16x8;
typedef __attribute__((ext_vector_type(4))) float f32x4;

__device__ __forceinline__ float bf2f(u16 u) {
    union { unsigned int i; float f; } x; x.i = ((unsigned int)u) << 16; return x.f;
}
__device__ __forceinline__ float bits2f(unsigned int u) {
    union { unsigned int i; float f; } x; x.i = u; return x.f;
}
__device__ __forceinline__ u16 f2bf(float f) {
    __hip_bfloat16 h = __float2bfloat16(f);
    return *reinterpret_cast<u16*>(&h);
}

// ---------------- merged prep ----------------
// blocks [0,256):   w_bin[cb][c] = wfc[cls][c*9+bin]                (bf16, pad cb>=243)
// blocks [256,320): w2s[o][cmid] = w2[cmid][o]*sc2[cmid]            (LDS transpose)
// blocks [320,576): w1ts[c][o]   = w1[o][c]*sc1[o]                  (LDS transpose)
// blocks [576,832): Anhwc[b][hw][c] = bf16(fmap_in[b][c][hw])       (LDS transpose)
// blocks [832,894): rw[roi][40]  = WX[3][6],WY[3][6],basepix,nx,ny
__global__ __launch_bounds__(256) void k_prep(
    const float* __restrict__ wfc, u16* __restrict__ w_bin,
    const float* __restrict__ w2, const float* __restrict__ g2,
    const float* __restrict__ v2, u16* __restrict__ w2s,
    const float* __restrict__ w1, const float* __restrict__ g1,
    const float* __restrict__ v1, u16* __restrict__ w1ts,
    const float* __restrict__ fmap_in, u16* __restrict__ anhwc,
    const float* __restrict__ boxes, float* __restrict__ rw_out)
{
    __shared__ float ld[64][197];
    float (*ld65)[65] = (float(*)[65])&ld[0][0];
    const int bid = blockIdx.x, t = threadIdx.x;
    if (bid < 256) {                       // w_bin
        int idx = bid * 256 + t;
        int cb = idx >> 8, c = idx & 255;
        int cls = cb / 9, bin = cb - cls * 9;
        w_bin[idx] = f2bf((cb < 243) ? wfc[cls * FEAT_ + c * 9 + bin] : 0.0f);
        return;
    }
    if (bid < 320) {                       // w2s: in w2[256][1024] -> out [1024][256]
        const int b2id = bid - 256;
        const int kt = b2id & 15, ct = b2id >> 4;
        const int rr = t >> 6, cc = t & 63;
        #pragma unroll
        for (int it = 0; it < 16; ++it) {
            int row = it * 4 + rr;
            ld65[row][cc] = w2[(size_t)(ct * 64 + row) * CIN_ + kt * 64 + cc];
        }
        __syncthreads();
        float sc = g2[ct * 64 + cc] * rsqrtf(v2[ct * 64 + cc] + 1e-5f);
        #pragma unroll
        for (int it = 0; it < 16; ++it) {
            int krow = it * 4 + rr;
            w2s[(size_t)(kt * 64 + krow) * CMID_ + ct * 64 + cc] = f2bf(ld65[cc][krow] * sc);
        }
        return;
    }
    if (bid < 576) {                       // w1ts: in w1[1024 o][1024 c] -> out [c][o]*sc1[o]
        const int b1id = bid - 320;
        const int ot = b1id & 15, ct = b1id >> 4;
        const int rr = t >> 6, cc = t & 63;
        #pragma unroll
        for (int it = 0; it < 16; ++it) {
            int row = it * 4 + rr;         // o_local
            ld65[row][cc] = w1[(size_t)(ot * 64 + row) * CIN_ + ct * 64 + cc];
        }
        __syncthreads();
        float sc = g1[ot * 64 + cc] * rsqrtf(v1[ot * 64 + cc] + 1e-5f);
        #pragma unroll
        for (int it = 0; it < 16; ++it) {
            int crow = it * 4 + rr;        // c_local
            w1ts[(size_t)(ct * 64 + crow) * CIN_ + ot * 64 + cc] = f2bf(ld65[cc][crow] * sc);
        }
        return;
    }
    if (bid < 832) {                       // NCHW -> NHWC bf16
        const int bn = bid - 576;
        const int b = bn >> 4, c0 = (bn & 15) << 6;
        const float* src = fmap_in + ((size_t)b * CIN_ + c0) * HW_;
        #pragma unroll
        for (int it = 0; it < 49; ++it) {
            int idx = it * 256 + t;
            int ci = idx / 196;
            int hw = idx - ci * 196;
            ld[ci][hw] = src[idx];
        }
        __syncthreads();
        u16* dst = anhwc + (size_t)b * HW_ * CIN_ + c0;
        #pragma unroll
        for (int it = 0; it < 49; ++it) {
            int idx = it * 256 + t;
            int hw = idx >> 6, ci = idx & 63;
            dst[(size_t)hw * CIN_ + ci] = f2bf(ld[ci][hw]);
        }
        return;
    }
    // per-roi separable pooling weights (thread = roi)
    const int r = (bid - 832) * 256 + t;
    if (r >= NROI_) return;
    const float* bxp = boxes + (size_t)r * 4;
    float x1 = bxp[0], y1 = bxp[1];
    float rwd = fmaxf(bxp[2] - x1, 1.0f), rhd = fmaxf(bxp[3] - y1, 1.0f);
    float sx = rwd * (1.0f / 3.0f), sy = rhd * (1.0f / 3.0f);
    const float OFFS[6] = {0.25f, 0.75f, 1.25f, 1.75f, 2.25f, 2.75f};
    int xl[6], xh[6], yl[6], yh[6];
    float lx[6], hx[6], ly[6], hy[6];
    #pragma unroll
    for (int i = 0; i < 6; ++i) {
        float xx = fmaxf(x1 + OFFS[i] * sx, 0.0f);
        xl[i] = min((int)xx, 13); xh[i] = min(xl[i] + 1, 13);
        float xv = (xl[i] == 13) ? 13.0f : xx;
        lx[i] = xv - (float)xl[i]; hx[i] = 1.0f - lx[i];
        float yy = fmaxf(y1 + OFFS[i] * sy, 0.0f);
        yl[i] = min((int)yy, 13); yh[i] = min(yl[i] + 1, 13);
        float yv = (yl[i] == 13) ? 13.0f : yy;
        ly[i] = yv - (float)yl[i]; hy[i] = 1.0f - ly[i];
    }
    const int xc0 = min(xl[0], 8), yr0 = min(yl[0], 8);
    float WX[3][6], WY[3][6];
    #pragma unroll
    for (int bi = 0; bi < 3; ++bi)
        #pragma unroll
        for (int c = 0; c < 6; ++c) { WX[bi][c] = 0.0f; WY[bi][c] = 0.0f; }
    #pragma unroll
    for (int i = 0; i < 6; ++i) {
        const int bi = i >> 1;
        #pragma unroll
        for (int c = 0; c < 6; ++c) {
            WX[bi][c] += (xl[i] - xc0 == c ? hx[i] : 0.0f)
                       + (xh[i] - xc0 == c ? lx[i] : 0.0f);
            WY[bi][c] += (yl[i] - yr0 == c ? hy[i] : 0.0f)
                       + (yh[i] - yr0 == c ? ly[i] : 0.0f);
        }
    }
    float* ro = rw_out + (size_t)r * 40;
    #pragma unroll
    for (int bi = 0; bi < 3; ++bi)
        #pragma unroll
        for (int c = 0; c < 6; ++c) { ro[bi * 6 + c] = WX[bi][c]; ro[18 + bi * 6 + c] = WY[bi][c]; }
    ro[36] = (float)(yr0 * 14 + xc0);     // window base pixel
    ro[37] = (float)(xh[5] - xc0 + 1);    // nx: used columns (<= 6)
    ro[38] = (float)(yh[5] - yr0 + 1);    // ny: used rows (<= 6)
}

// ---------------- generic split-K-4 GEMM + (bid>=nct) cfc branch --------------
// 1024 thr = 4 x (4-wave 64x64 sub-GEMM over K/4). BK=64, reg-prefetch. The
// reduction scratch aliases As (dead after the last MFMA barrier) to keep LDS
// at 74 KB. Doubles waves/SIMD vs the 512-thr version on <=256-block grids.
template<bool WITH_CFC>
__global__ __launch_bounds__(1024) void k_gemm_sk(
    const u16* __restrict__ A, const u16* __restrict__ Bw, u16* __restrict__ outp,
    int N, int K, int nct,
    const u16* __restrict__ w_bin, const u16* __restrict__ wG,
    const float* __restrict__ g1, const float* __restrict__ b1,
    const float* __restrict__ m1, const float* __restrict__ v1,
    const float* __restrict__ g2, const float* __restrict__ b2,
    const float* __restrict__ m2, const float* __restrict__ v2,
    const float* __restrict__ bfc, float* __restrict__ cfc)
{
    __shared__ u16 As[4][64][72];
    __shared__ u16 Bs[4][64][72];
    const int bid = blockIdx.x;
    if (WITH_CFC && bid >= nct) {
        __shared__ float ps[4];
        const int cls = bid - nct, t = threadIdx.x;
        if (t < 256) {
            float bi2 = b2[t] - m2[t] * (g2[t] * rsqrtf(v2[t] + 1e-5f));
            float s = 0.0f;
            #pragma unroll
            for (int bin = 0; bin < 9; ++bin)
                s += bf2f(w_bin[(cls * 9 + bin) * 256 + t]) * bi2;
            #pragma unroll
            for (int j = 0; j < 4; ++j) {
                int o = t + 256 * j;
                float bi1 = b1[o] - m1[o] * (g1[o] * rsqrtf(v1[o] + 1e-5f));
                #pragma unroll
                for (int bin = 0; bin < 9; ++bin)
                    s += bf2f(wG[(size_t)(cls * 9 + bin) * CIN_ + o]) * bi1;
            }
            #pragma unroll
            for (int o = 32; o > 0; o >>= 1) s += __shfl_xor(s, o, 64);
            if ((t & 63) == 0) ps[t >> 6] = s;
        }
        __syncthreads();
        if (threadIdx.x == 0) cfc[cls] = bfc[cls] + ps[0] + ps[1] + ps[2] + ps[3];
        return;
    }
    const int colt = bid % (N >> 6), rowt = bid / (N >> 6);
    const int row0 = rowt * 64, col0 = colt * 64;
    const int t = threadIdx.x, kw = t >> 8, tt = t & 255;
    const int wave = tt >> 6, lane = tt & 63;
    const int wr = (wave >> 1) * 32, wc = (wave & 1) * 32;
    const int fr = lane & 15, fk = (lane >> 4) * 8;
    const int sr = tt >> 2, sk = (tt & 3) * 16;
    const int Kq = K >> 2;
    const int nkt = Kq >> 6;
    f32x4 acc[2][2] = {};
    const u16* Ap = A + (size_t)(row0 + sr) * K + kw * Kq + sk;
    const u16* Bp = Bw + (size_t)(col0 + sr) * K + kw * Kq + sk;
    uint4 pa0 = *reinterpret_cast<const uint4*>(Ap);
    uint4 pa1 = *reinterpret_cast<const uint4*>(Ap + 8);
    uint4 pb0 = *reinterpret_cast<const uint4*>(Bp);
    uint4 pb1 = *reinterpret_cast<const uint4*>(Bp + 8);
    for (int kt = 0; kt < nkt; ++kt) {
        *reinterpret_cast<uint4*>(&As[kw][sr][sk]) = pa0;
        *reinterpret_cast<uint4*>(&As[kw][sr][sk + 8]) = pa1;
        *reinterpret_cast<uint4*>(&Bs[kw][sr][sk]) = pb0;
        *reinterpret_cast<uint4*>(&Bs[kw][sr][sk + 8]) = pb1;
        __syncthreads();
        if (kt < nkt - 1) {
            const int k0 = (kt + 1) * 64;
            pa0 = *reinterpret_cast<const uint4*>(Ap + k0);
            pa1 = *reinterpret_cast<const uint4*>(Ap + k0 + 8);
            pb0 = *reinterpret_cast<const uint4*>(Bp + k0);
            pb1 = *reinterpret_cast<const uint4*>(Bp + k0 + 8);
        }
        #pragma unroll
        for (int kk = 0; kk < 2; ++kk) {
            const int ko = fk + kk * 32;
            bf16x8 af0 = *reinterpret_cast<bf16x8*>(&As[kw][wr + fr][ko]);
            bf16x8 af1 = *reinterpret_cast<bf16x8*>(&As[kw][wr + 16 + fr][ko]);
            bf16x8 bf0 = *reinterpret_cast<bf16x8*>(&Bs[kw][wc + fr][ko]);
            bf16x8 bf1 = *reinterpret_cast<bf16x8*>(&Bs[kw][wc + 16 + fr][ko]);
            acc[0][0] = __builtin_amdgcn_mfma_f32_16x16x32_bf16(af0, bf0, acc[0][0], 0, 0, 0);
            acc[0][1] = __builtin_amdgcn_mfma_f32_16x16x32_bf16(af0, bf1, acc[0][1], 0, 0, 0);
            acc[1][0] = __builtin_amdgcn_mfma_f32_16x16x32_bf16(af1, bf0, acc[1][0], 0, 0, 0);
            acc[1][1] = __builtin_amdgcn_mfma_f32_16x16x32_bf16(af1, bf1, acc[1][1], 0, 0, 0);
        }
        __syncthreads();
    }
    // red aliases As (dead now; barrier above separates last reads from writes)
    float* red = (float*)&As[0][0][0];
    if (kw != 0) {
        #pragma unroll
        for (int mi = 0; mi < 2; ++mi)
            #pragma unroll
            for (int ni = 0; ni < 2; ++ni)
                #pragma unroll
                for (int rgi = 0; rgi < 4; ++rgi)
                    red[((kw - 1) * 4 + wave) * 1024 + lane * 16 + (mi * 2 + ni) * 4 + rgi]
                        = acc[mi][ni][rgi];
    }
    __syncthreads();
    if (kw == 0) {
        #pragma unroll
        for (int mi = 0; mi < 2; ++mi) {
            #pragma unroll
            for (int ni = 0; ni < 2; ++ni) {
                int col = col0 + wc + ni * 16 + fr;
                #pragma unroll
                for (int rgi = 0; rgi < 4; ++rgi) {
                    int row = row0 + wr + mi * 16 + (lane >> 4) * 4 + rgi;
                    int ri = wave * 1024 + lane * 16 + (mi * 2 + ni) * 4 + rgi;
                    float s = acc[mi][ni][rgi] + red[ri] + red[4096 + ri] + red[8192 + ri];
                    outp[(size_t)row * N + col] = f2bf(s);
                }
            }
        }
    }
}

// ---------------- K3: roi pooling on bf16 G (precomputed weights) -> logits ----------
// Variable window: nx,ny <= 6 are wave-uniform -> unrolled loops with uniform break
// skip zero-weight columns/rows (~50% of loads on average). Bitwise-identical output.
__global__ __launch_bounds__(256) void k_roi_logits(
    const float* __restrict__ rw, const u16* __restrict__ G,
    const float* __restrict__ cfc, float* __restrict__ out)
{
    __shared__ float sred[4][260];
    const int t = threadIdx.x, w = t >> 6, lane = t & 63;
    const int r = blockIdx.x * 4 + w;
    const int b = r / ROIS_;
    const float* rwp = rw + (size_t)r * 40;
    float WX[3][6], WY[3][6];
    #pragma unroll
    for (int q = 0; q < 9; ++q) {
        f32x4 v = *reinterpret_cast<const f32x4*>(rwp + q * 4);
        #pragma unroll
        for (int j = 0; j < 4; ++j) {
            int idx = q * 4 + j;                       // 0..35
            if (idx < 18) WX[idx / 6][idx % 6] = v[j];
            else          WY[(idx - 18) / 6][(idx - 18) % 6] = v[j];
        }
    }
    const int basepix = (int)rwp[36];
    const int nx = (int)rwp[37], ny = (int)rwp[38];

    int bxj[4], byj[4];
    #pragma unroll
    for (int j = 0; j < 4; ++j) {
        int cb = lane * 4 + j;
        int cls = cb / 9;
        int bin = cb - cls * 9;
        bxj[j] = bin % 3; byj[j] = bin / 3;
    }
    f32x4 wx4[6], wy4[6];
    #pragma unroll
    for (int q = 0; q < 6; ++q) {
        #pragma unroll
        for (int j = 0; j < 4; ++j) {
            wx4[q][j] = (bxj[j] == 0) ? WX[0][q] : ((bxj[j] == 1) ? WX[1][q] : WX[2][q]);
            wy4[q][j] = (byj[j] == 0) ? WY[0][q] : ((byj[j] == 1) ? WY[1][q] : WY[2][q]);
        }
    }

    const u16* base = G + ((size_t)b * HW_ + basepix) * NCB_ + lane * 4;
    f32x4 acc = {};
    #pragma unroll
    for (int rr = 0; rr < 6; ++rr) {
        if (rr >= ny) break;               // wave-uniform
        const u16* rp = base + rr * (14 * NCB_);
        f32x4 tmp = {};
        #pragma unroll
        for (int cc = 0; cc < 6; ++cc) {
            if (cc >= nx) break;           // wave-uniform
            uint2 gu = *reinterpret_cast<const uint2*>(rp + cc * NCB_);
            f32x4 g;
            g[0] = bits2f(gu.x << 16); g[1] = bits2f(gu.x & 0xFFFF0000u);
            g[2] = bits2f(gu.y << 16); g[3] = bits2f(gu.y & 0xFFFF0000u);
            tmp += g * wx4[cc];
        }
        acc += tmp * wy4[rr];
    }
    acc *= 0.25f;
    #pragma unroll
    for (int j = 0; j < 4; ++j) sred[w][lane * 4 + j] = acc[j];
    __syncthreads();
    if (lane < NCLS_) {
        float s = cfc[lane];
        #pragma unroll
        for (int bin = 0; bin < 9; ++bin) s += sred[w][lane * 9 + bin];
        out[(size_t)r * NCLS_ + lane] = s;
    }
}

extern "C" void kernel_launch(void* const* d_in, const int* in_sizes, int n_in,
                              void* d_out, int out_size, void* d_ws, size_t ws_size,
                              hipStream_t stream) {
    const float* boxes   = (const float*)d_in[0];
    const float* fmap_in = (const float*)d_in[1];
    const float* w1 = (const float*)d_in[2];
    const float* g1 = (const float*)d_in[3];
    const float* b1 = (const float*)d_in[4];
    const float* m1 = (const float*)d_in[5];
    const float* v1 = (const float*)d_in[6];
    const float* w2 = (const float*)d_in[7];
    const float* g2 = (const float*)d_in[8];
    const float* b2 = (const float*)d_in[9];
    const float* m2 = (const float*)d_in[10];
    const float* v2 = (const float*)d_in[11];
    const float* wfc = (const float*)d_in[12];
    const float* bfc = (const float*)d_in[13];

    char* ws = (char*)d_ws;
    u16*   Anhwc = (u16*)(ws + 0);                   //  6,422,528 B
    u16*   G16   = (u16*)(ws + 6422528);             //  1,605,632 B
    u16*   w_bin = (u16*)(ws + 8028160);             //    131,072 B
    u16*   w2s   = (u16*)(ws + 8159232);             //    524,288 B
    u16*   w1ts  = (u16*)(ws + 8683520);             //  2,097,152 B
    u16*   wG    = (u16*)(ws + 10780672);            //    524,288 B
    u16*   Wtot  = (u16*)(ws + 11304960);            //    524,288 B
    float* cfc   = (float*)(ws + 11829248);          //        128 B
    float* rw    = (float*)(ws + 11829376);          //  2,508,800 B (15680*40*4)

    hipLaunchKernelGGL(k_prep, dim3(832 + 62), dim3(256), 0, stream,
                       wfc, w_bin, w2, g2, v2, w2s, w1, g1, v1, w1ts, fmap_in, Anhwc,
                       boxes, rw);
    // wG[cb][o] = sum_cmid w_bin[cb][cmid] * w2s[o][cmid]   (M=256, N=1024, K=256)
    hipLaunchKernelGGL((k_gemm_sk<false>), dim3(64), dim3(1024), 0, stream,
                       w_bin, w2s, wG, CIN_, CMID_, 64,
                       nullptr, nullptr, nullptr, nullptr, nullptr, nullptr,
                       nullptr, nullptr, nullptr, nullptr, nullptr, nullptr);
    // Wtot[cb][c] = sum_o wG[cb][o] * w1ts[c][o]  (64 blocks) + cfc (27 blocks)
    hipLaunchKernelGGL((k_gemm_sk<true>), dim3(64 + NCLS_), dim3(1024), 0, stream,
                       wG, w1ts, Wtot, CIN_, CIN_, 64,
                       w_bin, wG, g1, b1, m1, v1, g2, b2, m2, v2, bfc, cfc);
    // G16[m][cb] = sum_c Anhwc[m][c] * Wtot[cb][c]          (M=3136, N=256, K=1024)
    hipLaunchKernelGGL((k_gemm_sk<false>), dim3(4 * 49), dim3(1024), 0, stream,
                       Anhwc, Wtot, G16, NCB_, CIN_, 196,
                       nullptr, nullptr, nullptr, nullptr, nullptr, nullptr,
                       nullptr, nullptr, nullptr, nullptr, nullptr, nullptr);
    hipLaunchKernelGGL(k_roi_logits, dim3(NROI_ / 4), dim3(256), 0, stream,
                       rw, G16, cfc, (float*)d_out);
}

// Round 18
// 60.870 us; speedup vs baseline: 1.0889x; 1.0889x over previous
//
#include <hip/hip_runtime.h>
#include <hip/hip_bf16.h>
#include <math.h>

#define H_ 14
#define W_ 14
#define HW_ 196
#define CIN_ 1024
#define CMID_ 256
#define NCLS_ 27
#define NB_ 16
#define ROIS_ 980
#define M_ 3136
#define FEAT_ 2304
#define NROI_ (NB_ * ROIS_)   // 15680
#define NCB_ 256              // padded cb = cls*9+bin (243 real)

typedef unsigned short u16;
typedef __attribute__((ext_vector_type(8))) short bf16x8;
typedef __attribute__((ext_vector_type(4))) float f32x4;

__device__ __forceinline__ float bf2f(u16 u) {
    union { unsigned int i; float f; } x; x.i = ((unsigned int)u) << 16; return x.f;
}
__device__ __forceinline__ float bits2f(unsigned int u) {
    union { unsigned int i; float f; } x; x.i = u; return x.f;
}
__device__ __forceinline__ u16 f2bf(float f) {
    __hip_bfloat16 h = __float2bfloat16(f);
    return *reinterpret_cast<u16*>(&h);
}

// ---------------- merged prep ----------------
// blocks [0,256):   w_bin[cb][c] = wfc[cls][c*9+bin]                (bf16, pad cb>=243)
// blocks [256,320): w2s[o][cmid] = w2[cmid][o]*sc2[cmid]            (LDS transpose)
// blocks [320,576): w1ts[c][o]   = w1[o][c]*sc1[o]                  (LDS transpose)
// blocks [576,832): Anhwc[b][hw][c] = bf16(fmap_in[b][c][hw])       (LDS transpose)
// blocks [832,894): rw[roi][40]  = WX[3][6],WY[3][6],basepix,nx,ny
__global__ __launch_bounds__(256) void k_prep(
    const float* __restrict__ wfc, u16* __restrict__ w_bin,
    const float* __restrict__ w2, const float* __restrict__ g2,
    const float* __restrict__ v2, u16* __restrict__ w2s,
    const float* __restrict__ w1, const float* __restrict__ g1,
    const float* __restrict__ v1, u16* __restrict__ w1ts,
    const float* __restrict__ fmap_in, u16* __restrict__ anhwc,
    const float* __restrict__ boxes, float* __restrict__ rw_out)
{
    __shared__ float ld[64][197];
    float (*ld65)[65] = (float(*)[65])&ld[0][0];
    const int bid = blockIdx.x, t = threadIdx.x;
    if (bid < 256) {                       // w_bin
        int idx = bid * 256 + t;
        int cb = idx >> 8, c = idx & 255;
        int cls = cb / 9, bin = cb - cls * 9;
        w_bin[idx] = f2bf((cb < 243) ? wfc[cls * FEAT_ + c * 9 + bin] : 0.0f);
        return;
    }
    if (bid < 320) {                       // w2s: in w2[256][1024] -> out [1024][256]
        const int b2id = bid - 256;
        const int kt = b2id & 15, ct = b2id >> 4;
        const int rr = t >> 6, cc = t & 63;
        #pragma unroll
        for (int it = 0; it < 16; ++it) {
            int row = it * 4 + rr;
            ld65[row][cc] = w2[(size_t)(ct * 64 + row) * CIN_ + kt * 64 + cc];
        }
        __syncthreads();
        float sc = g2[ct * 64 + cc] * rsqrtf(v2[ct * 64 + cc] + 1e-5f);
        #pragma unroll
        for (int it = 0; it < 16; ++it) {
            int krow = it * 4 + rr;
            w2s[(size_t)(kt * 64 + krow) * CMID_ + ct * 64 + cc] = f2bf(ld65[cc][krow] * sc);
        }
        return;
    }
    if (bid < 576) {                       // w1ts: in w1[1024 o][1024 c] -> out [c][o]*sc1[o]
        const int b1id = bid - 320;
        const int ot = b1id & 15, ct = b1id >> 4;
        const int rr = t >> 6, cc = t & 63;
        #pragma unroll
        for (int it = 0; it < 16; ++it) {
            int row = it * 4 + rr;         // o_local
            ld65[row][cc] = w1[(size_t)(ot * 64 + row) * CIN_ + ct * 64 + cc];
        }
        __syncthreads();
        float sc = g1[ot * 64 + cc] * rsqrtf(v1[ot * 64 + cc] + 1e-5f);
        #pragma unroll
        for (int it = 0; it < 16; ++it) {
            int crow = it * 4 + rr;        // c_local
            w1ts[(size_t)(ct * 64 + crow) * CIN_ + ot * 64 + cc] = f2bf(ld65[cc][crow] * sc);
        }
        return;
    }
    if (bid < 832) {                       // NCHW -> NHWC bf16
        const int bn = bid - 576;
        const int b = bn >> 4, c0 = (bn & 15) << 6;
        const float* src = fmap_in + ((size_t)b * CIN_ + c0) * HW_;
        #pragma unroll
        for (int it = 0; it < 49; ++it) {
            int idx = it * 256 + t;
            int ci = idx / 196;
            int hw = idx - ci * 196;
            ld[ci][hw] = src[idx];
        }
        __syncthreads();
        u16* dst = anhwc + (size_t)b * HW_ * CIN_ + c0;
        #pragma unroll
        for (int it = 0; it < 49; ++it) {
            int idx = it * 256 + t;
            int hw = idx >> 6, ci = idx & 63;
            dst[(size_t)hw * CIN_ + ci] = f2bf(ld[ci][hw]);
        }
        return;
    }
    // per-roi separable pooling weights (thread = roi)
    const int r = (bid - 832) * 256 + t;
    if (r >= NROI_) return;
    const float* bxp = boxes + (size_t)r * 4;
    float x1 = bxp[0], y1 = bxp[1];
    float rwd = fmaxf(bxp[2] - x1, 1.0f), rhd = fmaxf(bxp[3] - y1, 1.0f);
    float sx = rwd * (1.0f / 3.0f), sy = rhd * (1.0f / 3.0f);
    const float OFFS[6] = {0.25f, 0.75f, 1.25f, 1.75f, 2.25f, 2.75f};
    int xl[6], xh[6], yl[6], yh[6];
    float lx[6], hx[6], ly[6], hy[6];
    #pragma unroll
    for (int i = 0; i < 6; ++i) {
        float xx = fmaxf(x1 + OFFS[i] * sx, 0.0f);
        xl[i] = min((int)xx, 13); xh[i] = min(xl[i] + 1, 13);
        float xv = (xl[i] == 13) ? 13.0f : xx;
        lx[i] = xv - (float)xl[i]; hx[i] = 1.0f - lx[i];
        float yy = fmaxf(y1 + OFFS[i] * sy, 0.0f);
        yl[i] = min((int)yy, 13); yh[i] = min(yl[i] + 1, 13);
        float yv = (yl[i] == 13) ? 13.0f : yy;
        ly[i] = yv - (float)yl[i]; hy[i] = 1.0f - ly[i];
    }
    const int xc0 = min(xl[0], 8), yr0 = min(yl[0], 8);
    float WX[3][6], WY[3][6];
    #pragma unroll
    for (int bi = 0; bi < 3; ++bi)
        #pragma unroll
        for (int c = 0; c < 6; ++c) { WX[bi][c] = 0.0f; WY[bi][c] = 0.0f; }
    #pragma unroll
    for (int i = 0; i < 6; ++i) {
        const int bi = i >> 1;
        #pragma unroll
        for (int c = 0; c < 6; ++c) {
            WX[bi][c] += (xl[i] - xc0 == c ? hx[i] : 0.0f)
                       + (xh[i] - xc0 == c ? lx[i] : 0.0f);
            WY[bi][c] += (yl[i] - yr0 == c ? hy[i] : 0.0f)
                       + (yh[i] - yr0 == c ? ly[i] : 0.0f);
        }
    }
    float* ro = rw_out + (size_t)r * 40;
    #pragma unroll
    for (int bi = 0; bi < 3; ++bi)
        #pragma unroll
        for (int c = 0; c < 6; ++c) { ro[bi * 6 + c] = WX[bi][c]; ro[18 + bi * 6 + c] = WY[bi][c]; }
    ro[36] = (float)(yr0 * 14 + xc0);     // window base pixel
    ro[37] = (float)(xh[5] - xc0 + 1);    // nx: used columns (<= 6)
    ro[38] = (float)(yh[5] - yr0 + 1);    // ny: used rows (<= 6)
}

// ---------------- generic split-K GEMM + (bid>=nct) cfc branch --------------
// 512 thr = 2 x (4-wave 64x64 sub-GEMM over K/2). BK=64, reg-prefetch (R9 structure).
template<bool WITH_CFC>
__global__ __launch_bounds__(512) void k_gemm_sk(
    const u16* __restrict__ A, const u16* __restrict__ Bw, u16* __restrict__ outp,
    int N, int K, int nct,
    const u16* __restrict__ w_bin, const u16* __restrict__ wG,
    const float* __restrict__ g1, const float* __restrict__ b1,
    const float* __restrict__ m1, const float* __restrict__ v1,
    const float* __restrict__ g2, const float* __restrict__ b2,
    const float* __restrict__ m2, const float* __restrict__ v2,
    const float* __restrict__ bfc, float* __restrict__ cfc)
{
    __shared__ u16 As[2][64][72];
    __shared__ u16 Bs[2][64][72];
    __shared__ float red[4096];
    const int bid = blockIdx.x;
    if (WITH_CFC && bid >= nct) {
        __shared__ float ps[4];
        const int cls = bid - nct, t = threadIdx.x;
        if (t < 256) {
            float bi2 = b2[t] - m2[t] * (g2[t] * rsqrtf(v2[t] + 1e-5f));
            float s = 0.0f;
            #pragma unroll
            for (int bin = 0; bin < 9; ++bin)
                s += bf2f(w_bin[(cls * 9 + bin) * 256 + t]) * bi2;
            #pragma unroll
            for (int j = 0; j < 4; ++j) {
                int o = t + 256 * j;
                float bi1 = b1[o] - m1[o] * (g1[o] * rsqrtf(v1[o] + 1e-5f));
                #pragma unroll
                for (int bin = 0; bin < 9; ++bin)
                    s += bf2f(wG[(size_t)(cls * 9 + bin) * CIN_ + o]) * bi1;
            }
            #pragma unroll
            for (int o = 32; o > 0; o >>= 1) s += __shfl_xor(s, o, 64);
            if ((t & 63) == 0) ps[t >> 6] = s;
        }
        __syncthreads();
        if (threadIdx.x == 0) cfc[cls] = bfc[cls] + ps[0] + ps[1] + ps[2] + ps[3];
        return;
    }
    const int colt = bid % (N >> 6), rowt = bid / (N >> 6);
    const int row0 = rowt * 64, col0 = colt * 64;
    const int t = threadIdx.x, kw = t >> 8, tt = t & 255;
    const int wave = tt >> 6, lane = tt & 63;
    const int wr = (wave >> 1) * 32, wc = (wave & 1) * 32;
    const int fr = lane & 15, fk = (lane >> 4) * 8;
    const int sr = tt >> 2, sk = (tt & 3) * 16;
    const int Kh = K >> 1;
    const int nkt = Kh >> 6;
    f32x4 acc[2][2] = {};
    const u16* Ap = A + (size_t)(row0 + sr) * K + kw * Kh + sk;
    const u16* Bp = Bw + (size_t)(col0 + sr) * K + kw * Kh + sk;
    uint4 pa0 = *reinterpret_cast<const uint4*>(Ap);
    uint4 pa1 = *reinterpret_cast<const uint4*>(Ap + 8);
    uint4 pb0 = *reinterpret_cast<const uint4*>(Bp);
    uint4 pb1 = *reinterpret_cast<const uint4*>(Bp + 8);
    for (int kt = 0; kt < nkt; ++kt) {
        *reinterpret_cast<uint4*>(&As[kw][sr][sk]) = pa0;
        *reinterpret_cast<uint4*>(&As[kw][sr][sk + 8]) = pa1;
        *reinterpret_cast<uint4*>(&Bs[kw][sr][sk]) = pb0;
        *reinterpret_cast<uint4*>(&Bs[kw][sr][sk + 8]) = pb1;
        __syncthreads();
        if (kt < nkt - 1) {
            const int k0 = (kt + 1) * 64;
            pa0 = *reinterpret_cast<const uint4*>(Ap + k0);
            pa1 = *reinterpret_cast<const uint4*>(Ap + k0 + 8);
            pb0 = *reinterpret_cast<const uint4*>(Bp + k0);
            pb1 = *reinterpret_cast<const uint4*>(Bp + k0 + 8);
        }
        #pragma unroll
        for (int kk = 0; kk < 2; ++kk) {
            const int ko = fk + kk * 32;
            bf16x8 af0 = *reinterpret_cast<bf16x8*>(&As[kw][wr + fr][ko]);
            bf16x8 af1 = *reinterpret_cast<bf16x8*>(&As[kw][wr + 16 + fr][ko]);
            bf16x8 bf0 = *reinterpret_cast<bf16x8*>(&Bs[kw][wc + fr][ko]);
            bf16x8 bf1 = *reinterpret_cast<bf16x8*>(&Bs[kw][wc + 16 + fr][ko]);
            acc[0][0] = __builtin_amdgcn_mfma_f32_16x16x32_bf16(af0, bf0, acc[0][0], 0, 0, 0);
            acc[0][1] = __builtin_amdgcn_mfma_f32_16x16x32_bf16(af0, bf1, acc[0][1], 0, 0, 0);
            acc[1][0] = __builtin_amdgcn_mfma_f32_16x16x32_bf16(af1, bf0, acc[1][0], 0, 0, 0);
            acc[1][1] = __builtin_amdgcn_mfma_f32_16x16x32_bf16(af1, bf1, acc[1][1], 0, 0, 0);
        }
        __syncthreads();
    }
    if (kw == 1) {
        #pragma unroll
        for (int mi = 0; mi < 2; ++mi)
            #pragma unroll
            for (int ni = 0; ni < 2; ++ni)
                #pragma unroll
                for (int rgi = 0; rgi < 4; ++rgi)
                    red[wave * 1024 + lane * 16 + (mi * 2 + ni) * 4 + rgi] = acc[mi][ni][rgi];
    }
    __syncthreads();
    if (kw == 0) {
        #pragma unroll
        for (int mi = 0; mi < 2; ++mi) {
            #pragma unroll
            for (int ni = 0; ni < 2; ++ni) {
                int col = col0 + wc + ni * 16 + fr;
                #pragma unroll
                for (int rgi = 0; rgi < 4; ++rgi) {
                    int row = row0 + wr + mi * 16 + (lane >> 4) * 4 + rgi;
                    float s = acc[mi][ni][rgi]
                            + red[wave * 1024 + lane * 16 + (mi * 2 + ni) * 4 + rgi];
                    outp[(size_t)row * N + col] = f2bf(s);
                }
            }
        }
    }
}

// ---------------- K3: roi pooling on bf16 G (precomputed weights) -> logits ----------
// Branch-free window clamp: columns cc>=nx and rows rr>=ny have exactly-zero weight,
// so their load addresses are clamped to the last valid column/row -> duplicate loads
// hit L1 (no extra L2 traffic), all 36 loads still batch-issue. Bitwise-identical.
__global__ __launch_bounds__(256) void k_roi_logits(
    const float* __restrict__ rw, const u16* __restrict__ G,
    const float* __restrict__ cfc, float* __restrict__ out)
{
    __shared__ float sred[4][260];
    const int t = threadIdx.x, w = t >> 6, lane = t & 63;
    const int r = blockIdx.x * 4 + w;
    const int b = r / ROIS_;
    const float* rwp = rw + (size_t)r * 40;
    float WX[3][6], WY[3][6];
    #pragma unroll
    for (int q = 0; q < 9; ++q) {
        f32x4 v = *reinterpret_cast<const f32x4*>(rwp + q * 4);
        #pragma unroll
        for (int j = 0; j < 4; ++j) {
            int idx = q * 4 + j;                       // 0..35
            if (idx < 18) WX[idx / 6][idx % 6] = v[j];
            else          WY[(idx - 18) / 6][(idx - 18) % 6] = v[j];
        }
    }
    const int basepix = (int)rwp[36];
    const int nx = (int)rwp[37], ny = (int)rwp[38];
    int coff[6], roff[6];
    #pragma unroll
    for (int q = 0; q < 6; ++q) {
        coff[q] = min(q, nx - 1) * NCB_;
        roff[q] = min(q, ny - 1) * (14 * NCB_);
    }

    int bxj[4], byj[4];
    #pragma unroll
    for (int j = 0; j < 4; ++j) {
        int cb = lane * 4 + j;
        int cls = cb / 9;
        int bin = cb - cls * 9;
        bxj[j] = bin % 3; byj[j] = bin / 3;
    }
    f32x4 wx4[6], wy4[6];
    #pragma unroll
    for (int q = 0; q < 6; ++q) {
        #pragma unroll
        for (int j = 0; j < 4; ++j) {
            wx4[q][j] = (bxj[j] == 0) ? WX[0][q] : ((bxj[j] == 1) ? WX[1][q] : WX[2][q]);
            wy4[q][j] = (byj[j] == 0) ? WY[0][q] : ((byj[j] == 1) ? WY[1][q] : WY[2][q]);
        }
    }

    const u16* base = G + ((size_t)b * HW_ + basepix) * NCB_ + lane * 4;
    f32x4 acc = {};
    #pragma unroll
    for (int rr = 0; rr < 6; ++rr) {
        const u16* rp = base + roff[rr];
        f32x4 tmp = {};
        #pragma unroll
        for (int cc = 0; cc < 6; ++cc) {
            uint2 gu = *reinterpret_cast<const uint2*>(rp + coff[cc]);
            f32x4 g;
            g[0] = bits2f(gu.x << 16); g[1] = bits2f(gu.x & 0xFFFF0000u);
            g[2] = bits2f(gu.y << 16); g[3] = bits2f(gu.y & 0xFFFF0000u);
            tmp += g * wx4[cc];
        }
        acc += tmp * wy4[rr];
    }
    acc *= 0.25f;
    #pragma unroll
    for (int j = 0; j < 4; ++j) sred[w][lane * 4 + j] = acc[j];
    __syncthreads();
    if (lane < NCLS_) {
        float s = cfc[lane];
        #pragma unroll
        for (int bin = 0; bin < 9; ++bin) s += sred[w][lane * 9 + bin];
        out[(size_t)r * NCLS_ + lane] = s;
    }
}

extern "C" void kernel_launch(void* const* d_in, const int* in_sizes, int n_in,
                              void* d_out, int out_size, void* d_ws, size_t ws_size,
                              hipStream_t stream) {
    const float* boxes   = (const float*)d_in[0];
    const float* fmap_in = (const float*)d_in[1];
    const float* w1 = (const float*)d_in[2];
    const float* g1 = (const float*)d_in[3];
    const float* b1 = (const float*)d_in[4];
    const float* m1 = (const float*)d_in[5];
    const float* v1 = (const float*)d_in[6];
    const float* w2 = (const float*)d_in[7];
    const float* g2 = (const float*)d_in[8];
    const float* b2 = (const float*)d_in[9];
    const float* m2 = (const float*)d_in[10];
    const float* v2 = (const float*)d_in[11];
    const float* wfc = (const float*)d_in[12];
    const float* bfc = (const float*)d_in[13];

    char* ws = (char*)d_ws;
    u16*   Anhwc = (u16*)(ws + 0);                   //  6,422,528 B
    u16*   G16   = (u16*)(ws + 6422528);             //  1,605,632 B
    u16*   w_bin = (u16*)(ws + 8028160);             //    131,072 B
    u16*   w2s   = (u16*)(ws + 8159232);             //    524,288 B
    u16*   w1ts  = (u16*)(ws + 8683520);             //  2,097,152 B
    u16*   wG    = (u16*)(ws + 10780672);            //    524,288 B
    u16*   Wtot  = (u16*)(ws + 11304960);            //    524,288 B
    float* cfc   = (float*)(ws + 11829248);          //        128 B
    float* rw    = (float*)(ws + 11829376);          //  2,508,800 B (15680*40*4)

    hipLaunchKernelGGL(k_prep, dim3(832 + 62), dim3(256), 0, stream,
                       wfc, w_bin, w2, g2, v2, w2s, w1, g1, v1, w1ts, fmap_in, Anhwc,
                       boxes, rw);
    // wG[cb][o] = sum_cmid w_bin[cb][cmid] * w2s[o][cmid]   (M=256, N=1024, K=256)
    hipLaunchKernelGGL((k_gemm_sk<false>), dim3(64), dim3(512), 0, stream,
                       w_bin, w2s, wG, CIN_, CMID_, 64,
                       nullptr, nullptr, nullptr, nullptr, nullptr, nullptr,
                       nullptr, nullptr, nullptr, nullptr, nullptr, nullptr);
    // Wtot[cb][c] = sum_o wG[cb][o] * w1ts[c][o]  (64 blocks) + cfc (27 blocks)
    hipLaunchKernelGGL((k_gemm_sk<true>), dim3(64 + NCLS_), dim3(512), 0, stream,
                       wG, w1ts, Wtot, CIN_, CIN_, 64,
                       w_bin, wG, g1, b1, m1, v1, g2, b2, m2, v2, bfc, cfc);
    // G16[m][cb] = sum_c Anhwc[m][c] * Wtot[cb][c]          (M=3136, N=256, K=1024)
    hipLaunchKernelGGL((k_gemm_sk<false>), dim3(4 * 49), dim3(512), 0, stream,
                       Anhwc, Wtot, G16, NCB_, CIN_, 196,
                       nullptr, nullptr, nullptr, nullptr, nullptr, nullptr,
                       nullptr, nullptr, nullptr, nullptr, nullptr, nullptr);
    hipLaunchKernelGGL(k_roi_logits, dim3(NROI_ / 4), dim3(256), 0, stream,
                       rw, G16, cfc, (float*)d_out);
}

// Round 19
// 59.099 us; speedup vs baseline: 1.1215x; 1.0300x over previous
//
#include <hip/hip_runtime.h>
#include <hip/hip_bf16.h>
#include <math.h>

#define H_ 14
#define W_ 14
#define HW_ 196
#define CIN_ 1024
#define CMID_ 256
#define NCLS_ 27
#define NB_ 16
#define ROIS_ 980
#define M_ 3136
#define FEAT_ 2304
#define NROI_ (NB_ * ROIS_)   // 15680
#define NCB_ 256              // padded cb = cls*9+bin (243 real)

typedef unsigned short u16;
typedef __attribute__((ext_vector_type(8))) short bf16x8;
typedef __attribute__((ext_vector_type(4))) float f32x4;

__device__ __forceinline__ float bf2f(u16 u) {
    union { unsigned int i; float f; } x; x.i = ((unsigned int)u) << 16; return x.f;
}
__device__ __forceinline__ float bits2f(unsigned int u) {
    union { unsigned int i; float f; } x; x.i = u; return x.f;
}
__device__ __forceinline__ u16 f2bf(float f) {
    __hip_bfloat16 h = __float2bfloat16(f);
    return *reinterpret_cast<u16*>(&h);
}

// ---------------- merged prep ----------------
// blocks [0,256):   w_bin[cb][c] = wfc[cls][c*9+bin]                (bf16, pad cb>=243)
// blocks [256,320): w2s[o][cmid] = w2[cmid][o]*sc2[cmid]            (LDS transpose)
// blocks [320,576): w1ts[c][o]   = w1[o][c]*sc1[o]                  (LDS transpose)
// blocks [576,832): Anhwc[b][hw][c] = bf16(fmap_in[b][c][hw])       (LDS transpose)
// blocks [832,894): rw[roi][40]  = WX[3][6],WY[3][6],basepix
__global__ __launch_bounds__(256) void k_prep(
    const float* __restrict__ wfc, u16* __restrict__ w_bin,
    const float* __restrict__ w2, const float* __restrict__ g2,
    const float* __restrict__ v2, u16* __restrict__ w2s,
    const float* __restrict__ w1, const float* __restrict__ g1,
    const float* __restrict__ v1, u16* __restrict__ w1ts,
    const float* __restrict__ fmap_in, u16* __restrict__ anhwc,
    const float* __restrict__ boxes, float* __restrict__ rw_out)
{
    __shared__ float ld[64][197];
    float (*ld65)[65] = (float(*)[65])&ld[0][0];
    const int bid = blockIdx.x, t = threadIdx.x;
    if (bid < 256) {                       // w_bin
        int idx = bid * 256 + t;
        int cb = idx >> 8, c = idx & 255;
        int cls = cb / 9, bin = cb - cls * 9;
        w_bin[idx] = f2bf((cb < 243) ? wfc[cls * FEAT_ + c * 9 + bin] : 0.0f);
        return;
    }
    if (bid < 320) {                       // w2s: in w2[256][1024] -> out [1024][256]
        const int b2id = bid - 256;
        const int kt = b2id & 15, ct = b2id >> 4;
        const int rr = t >> 6, cc = t & 63;
        #pragma unroll
        for (int it = 0; it < 16; ++it) {
            int row = it * 4 + rr;
            ld65[row][cc] = w2[(size_t)(ct * 64 + row) * CIN_ + kt * 64 + cc];
        }
        __syncthreads();
        float sc = g2[ct * 64 + cc] * rsqrtf(v2[ct * 64 + cc] + 1e-5f);
        #pragma unroll
        for (int it = 0; it < 16; ++it) {
            int krow = it * 4 + rr;
            w2s[(size_t)(kt * 64 + krow) * CMID_ + ct * 64 + cc] = f2bf(ld65[cc][krow] * sc);
        }
        return;
    }
    if (bid < 576) {                       // w1ts: in w1[1024 o][1024 c] -> out [c][o]*sc1[o]
        const int b1id = bid - 320;
        const int ot = b1id & 15, ct = b1id >> 4;
        const int rr = t >> 6, cc = t & 63;
        #pragma unroll
        for (int it = 0; it < 16; ++it) {
            int row = it * 4 + rr;         // o_local
            ld65[row][cc] = w1[(size_t)(ot * 64 + row) * CIN_ + ct * 64 + cc];
        }
        __syncthreads();
        float sc = g1[ot * 64 + cc] * rsqrtf(v1[ot * 64 + cc] + 1e-5f);
        #pragma unroll
        for (int it = 0; it < 16; ++it) {
            int crow = it * 4 + rr;        // c_local
            w1ts[(size_t)(ct * 64 + crow) * CIN_ + ot * 64 + cc] = f2bf(ld65[cc][crow] * sc);
        }
        return;
    }
    if (bid < 832) {                       // NCHW -> NHWC bf16
        const int bn = bid - 576;
        const int b = bn >> 4, c0 = (bn & 15) << 6;
        const float* src = fmap_in + ((size_t)b * CIN_ + c0) * HW_;
        #pragma unroll
        for (int it = 0; it < 49; ++it) {
            int idx = it * 256 + t;
            int ci = idx / 196;
            int hw = idx - ci * 196;
            ld[ci][hw] = src[idx];
        }
        __syncthreads();
        u16* dst = anhwc + (size_t)b * HW_ * CIN_ + c0;
        #pragma unroll
        for (int it = 0; it < 49; ++it) {
            int idx = it * 256 + t;
            int hw = idx >> 6, ci = idx & 63;
            dst[(size_t)hw * CIN_ + ci] = f2bf(ld[ci][hw]);
        }
        return;
    }
    // per-roi separable pooling weights (thread = roi)
    const int r = (bid - 832) * 256 + t;
    if (r >= NROI_) return;
    const float* bxp = boxes + (size_t)r * 4;
    float x1 = bxp[0], y1 = bxp[1];
    float rwd = fmaxf(bxp[2] - x1, 1.0f), rhd = fmaxf(bxp[3] - y1, 1.0f);
    float sx = rwd * (1.0f / 3.0f), sy = rhd * (1.0f / 3.0f);
    const float OFFS[6] = {0.25f, 0.75f, 1.25f, 1.75f, 2.25f, 2.75f};
    int xl[6], xh[6], yl[6], yh[6];
    float lx[6], hx[6], ly[6], hy[6];
    #pragma unroll
    for (int i = 0; i < 6; ++i) {
        float xx = fmaxf(x1 + OFFS[i] * sx, 0.0f);
        xl[i] = min((int)xx, 13); xh[i] = min(xl[i] + 1, 13);
        float xv = (xl[i] == 13) ? 13.0f : xx;
        lx[i] = xv - (float)xl[i]; hx[i] = 1.0f - lx[i];
        float yy = fmaxf(y1 + OFFS[i] * sy, 0.0f);
        yl[i] = min((int)yy, 13); yh[i] = min(yl[i] + 1, 13);
        float yv = (yl[i] == 13) ? 13.0f : yy;
        ly[i] = yv - (float)yl[i]; hy[i] = 1.0f - ly[i];
    }
    const int xc0 = min(xl[0], 8), yr0 = min(yl[0], 8);
    float WX[3][6], WY[3][6];
    #pragma unroll
    for (int bi = 0; bi < 3; ++bi)
        #pragma unroll
        for (int c = 0; c < 6; ++c) { WX[bi][c] = 0.0f; WY[bi][c] = 0.0f; }
    #pragma unroll
    for (int i = 0; i < 6; ++i) {
        const int bi = i >> 1;
        #pragma unroll
        for (int c = 0; c < 6; ++c) {
            WX[bi][c] += (xl[i] - xc0 == c ? hx[i] : 0.0f)
                       + (xh[i] - xc0 == c ? lx[i] : 0.0f);
            WY[bi][c] += (yl[i] - yr0 == c ? hy[i] : 0.0f)
                       + (yh[i] - yr0 == c ? ly[i] : 0.0f);
        }
    }
    float* ro = rw_out + (size_t)r * 40;
    #pragma unroll
    for (int bi = 0; bi < 3; ++bi)
        #pragma unroll
        for (int c = 0; c < 6; ++c) { ro[bi * 6 + c] = WX[bi][c]; ro[18 + bi * 6 + c] = WY[bi][c]; }
    ro[36] = (float)(yr0 * 14 + xc0);     // window base pixel
    ro[37] = (float)(xh[5] - xc0 + 1);    // nx (unused by consumer; kept for parity)
    ro[38] = (float)(yh[5] - yr0 + 1);    // ny (unused by consumer; kept for parity)
}

// ---------------- generic split-K GEMM + (bid>=nct) cfc branch --------------
// 512 thr = 2 x (4-wave 64x64 sub-GEMM over K/2). BK=64, reg-prefetch (R9 structure).
template<bool WITH_CFC>
__global__ __launch_bounds__(512) void k_gemm_sk(
    const u16* __restrict__ A, const u16* __restrict__ Bw, u16* __restrict__ outp,
    int N, int K, int nct,
    const u16* __restrict__ w_bin, const u16* __restrict__ wG,
    const float* __restrict__ g1, const float* __restrict__ b1,
    const float* __restrict__ m1, const float* __restrict__ v1,
    const float* __restrict__ g2, const float* __restrict__ b2,
    const float* __restrict__ m2, const float* __restrict__ v2,
    const float* __restrict__ bfc, float* __restrict__ cfc)
{
    __shared__ u16 As[2][64][72];
    __shared__ u16 Bs[2][64][72];
    __shared__ float red[4096];
    const int bid = blockIdx.x;
    if (WITH_CFC && bid >= nct) {
        __shared__ float ps[4];
        const int cls = bid - nct, t = threadIdx.x;
        if (t < 256) {
            float bi2 = b2[t] - m2[t] * (g2[t] * rsqrtf(v2[t] + 1e-5f));
            float s = 0.0f;
            #pragma unroll
            for (int bin = 0; bin < 9; ++bin)
                s += bf2f(w_bin[(cls * 9 + bin) * 256 + t]) * bi2;
            #pragma unroll
            for (int j = 0; j < 4; ++j) {
                int o = t + 256 * j;
                float bi1 = b1[o] - m1[o] * (g1[o] * rsqrtf(v1[o] + 1e-5f));
                #pragma unroll
                for (int bin = 0; bin < 9; ++bin)
                    s += bf2f(wG[(size_t)(cls * 9 + bin) * CIN_ + o]) * bi1;
            }
            #pragma unroll
            for (int o = 32; o > 0; o >>= 1) s += __shfl_xor(s, o, 64);
            if ((t & 63) == 0) ps[t >> 6] = s;
        }
        __syncthreads();
        if (threadIdx.x == 0) cfc[cls] = bfc[cls] + ps[0] + ps[1] + ps[2] + ps[3];
        return;
    }
    const int colt = bid % (N >> 6), rowt = bid / (N >> 6);
    const int row0 = rowt * 64, col0 = colt * 64;
    const int t = threadIdx.x, kw = t >> 8, tt = t & 255;
    const int wave = tt >> 6, lane = tt & 63;
    const int wr = (wave >> 1) * 32, wc = (wave & 1) * 32;
    const int fr = lane & 15, fk = (lane >> 4) * 8;
    const int sr = tt >> 2, sk = (tt & 3) * 16;
    const int Kh = K >> 1;
    const int nkt = Kh >> 6;
    f32x4 acc[2][2] = {};
    const u16* Ap = A + (size_t)(row0 + sr) * K + kw * Kh + sk;
    const u16* Bp = Bw + (size_t)(col0 + sr) * K + kw * Kh + sk;
    uint4 pa0 = *reinterpret_cast<const uint4*>(Ap);
    uint4 pa1 = *reinterpret_cast<const uint4*>(Ap + 8);
    uint4 pb0 = *reinterpret_cast<const uint4*>(Bp);
    uint4 pb1 = *reinterpret_cast<const uint4*>(Bp + 8);
    for (int kt = 0; kt < nkt; ++kt) {
        *reinterpret_cast<uint4*>(&As[kw][sr][sk]) = pa0;
        *reinterpret_cast<uint4*>(&As[kw][sr][sk + 8]) = pa1;
        *reinterpret_cast<uint4*>(&Bs[kw][sr][sk]) = pb0;
        *reinterpret_cast<uint4*>(&Bs[kw][sr][sk + 8]) = pb1;
        __syncthreads();
        if (kt < nkt - 1) {
            const int k0 = (kt + 1) * 64;
            pa0 = *reinterpret_cast<const uint4*>(Ap + k0);
            pa1 = *reinterpret_cast<const uint4*>(Ap + k0 + 8);
            pb0 = *reinterpret_cast<const uint4*>(Bp + k0);
            pb1 = *reinterpret_cast<const uint4*>(Bp + k0 + 8);
        }
        #pragma unroll
        for (int kk = 0; kk < 2; ++kk) {
            const int ko = fk + kk * 32;
            bf16x8 af0 = *reinterpret_cast<bf16x8*>(&As[kw][wr + fr][ko]);
            bf16x8 af1 = *reinterpret_cast<bf16x8*>(&As[kw][wr + 16 + fr][ko]);
            bf16x8 bf0 = *reinterpret_cast<bf16x8*>(&Bs[kw][wc + fr][ko]);
            bf16x8 bf1 = *reinterpret_cast<bf16x8*>(&Bs[kw][wc + 16 + fr][ko]);
            acc[0][0] = __builtin_amdgcn_mfma_f32_16x16x32_bf16(af0, bf0, acc[0][0], 0, 0, 0);
            acc[0][1] = __builtin_amdgcn_mfma_f32_16x16x32_bf16(af0, bf1, acc[0][1], 0, 0, 0);
            acc[1][0] = __builtin_amdgcn_mfma_f32_16x16x32_bf16(af1, bf0, acc[1][0], 0, 0, 0);
            acc[1][1] = __builtin_amdgcn_mfma_f32_16x16x32_bf16(af1, bf1, acc[1][1], 0, 0, 0);
        }
        __syncthreads();
    }
    if (kw == 1) {
        #pragma unroll
        for (int mi = 0; mi < 2; ++mi)
            #pragma unroll
            for (int ni = 0; ni < 2; ++ni)
                #pragma unroll
                for (int rgi = 0; rgi < 4; ++rgi)
                    red[wave * 1024 + lane * 16 + (mi * 2 + ni) * 4 + rgi] = acc[mi][ni][rgi];
    }
    __syncthreads();
    if (kw == 0) {
        #pragma unroll
        for (int mi = 0; mi < 2; ++mi) {
            #pragma unroll
            for (int ni = 0; ni < 2; ++ni) {
                int col = col0 + wc + ni * 16 + fr;
                #pragma unroll
                for (int rgi = 0; rgi < 4; ++rgi) {
                    int row = row0 + wr + mi * 16 + (lane >> 4) * 4 + rgi;
                    float s = acc[mi][ni][rgi]
                            + red[wave * 1024 + lane * 16 + (mi * 2 + ni) * 4 + rgi];
                    outp[(size_t)row * N + col] = f2bf(s);
                }
            }
        }
    }
}

// ---------------- K3: roi pooling on bf16 G (precomputed weights) -> logits ----------
__global__ __launch_bounds__(256) void k_roi_logits(
    const float* __restrict__ rw, const u16* __restrict__ G,
    const float* __restrict__ cfc, float* __restrict__ out)
{
    __shared__ float sred[4][260];
    const int t = threadIdx.x, w = t >> 6, lane = t & 63;
    const int r = blockIdx.x * 4 + w;
    const int b = r / ROIS_;
    const float* rwp = rw + (size_t)r * 40;
    float WX[3][6], WY[3][6];
    #pragma unroll
    for (int q = 0; q < 9; ++q) {
        f32x4 v = *reinterpret_cast<const f32x4*>(rwp + q * 4);
        #pragma unroll
        for (int j = 0; j < 4; ++j) {
            int idx = q * 4 + j;                       // 0..35
            if (idx < 18) WX[idx / 6][idx % 6] = v[j];
            else          WY[(idx - 18) / 6][(idx - 18) % 6] = v[j];
        }
    }
    const int basepix = (int)rwp[36];

    int bxj[4], byj[4];
    #pragma unroll
    for (int j = 0; j < 4; ++j) {
        int cb = lane * 4 + j;
        int cls = cb / 9;
        int bin = cb - cls * 9;
        bxj[j] = bin % 3; byj[j] = bin / 3;
    }
    f32x4 wx4[6], wy4[6];
    #pragma unroll
    for (int q = 0; q < 6; ++q) {
        #pragma unroll
        for (int j = 0; j < 4; ++j) {
            wx4[q][j] = (bxj[j] == 0) ? WX[0][q] : ((bxj[j] == 1) ? WX[1][q] : WX[2][q]);
            wy4[q][j] = (byj[j] == 0) ? WY[0][q] : ((byj[j] == 1) ? WY[1][q] : WY[2][q]);
        }
    }

    const u16* base = G + ((size_t)b * HW_ + basepix) * NCB_ + lane * 4;
    f32x4 acc = {};
    #pragma unroll
    for (int rr = 0; rr < 6; ++rr) {
        const u16* rp = base + rr * (14 * NCB_);
        f32x4 tmp = {};
        #pragma unroll
        for (int cc = 0; cc < 6; ++cc) {
            uint2 gu = *reinterpret_cast<const uint2*>(rp + cc * NCB_);
            f32x4 g;
            g[0] = bits2f(gu.x << 16); g[1] = bits2f(gu.x & 0xFFFF0000u);
            g[2] = bits2f(gu.y << 16); g[3] = bits2f(gu.y & 0xFFFF0000u);
            tmp += g * wx4[cc];
        }
        acc += tmp * wy4[rr];
    }
    acc *= 0.25f;
    #pragma unroll
    for (int j = 0; j < 4; ++j) sred[w][lane * 4 + j] = acc[j];
    __syncthreads();
    if (lane < NCLS_) {
        float s = cfc[lane];
        #pragma unroll
        for (int bin = 0; bin < 9; ++bin) s += sred[w][lane * 9 + bin];
        out[(size_t)r * NCLS_ + lane] = s;
    }
}

extern "C" void kernel_launch(void* const* d_in, const int* in_sizes, int n_in,
                              void* d_out, int out_size, void* d_ws, size_t ws_size,
                              hipStream_t stream) {
    const float* boxes   = (const float*)d_in[0];
    const float* fmap_in = (const float*)d_in[1];
    const float* w1 = (const float*)d_in[2];
    const float* g1 = (const float*)d_in[3];
    const float* b1 = (const float*)d_in[4];
    const float* m1 = (const float*)d_in[5];
    const float* v1 = (const float*)d_in[6];
    const float* w2 = (const float*)d_in[7];
    const float* g2 = (const float*)d_in[8];
    const float* b2 = (const float*)d_in[9];
    const float* m2 = (const float*)d_in[10];
    const float* v2 = (const float*)d_in[11];
    const float* wfc = (const float*)d_in[12];
    const float* bfc = (const float*)d_in[13];

    char* ws = (char*)d_ws;
    u16*   Anhwc = (u16*)(ws + 0);                   //  6,422,528 B
    u16*   G16   = (u16*)(ws + 6422528);             //  1,605,632 B
    u16*   w_bin = (u16*)(ws + 8028160);             //    131,072 B
    u16*   w2s   = (u16*)(ws + 8159232);             //    524,288 B
    u16*   w1ts  = (u16*)(ws + 8683520);             //  2,097,152 B
    u16*   wG    = (u16*)(ws + 10780672);            //    524,288 B
    u16*   Wtot  = (u16*)(ws + 11304960);            //    524,288 B
    float* cfc   = (float*)(ws + 11829248);          //        128 B
    float* rw    = (float*)(ws + 11829376);          //  2,508,800 B (15680*40*4)

    hipLaunchKernelGGL(k_prep, dim3(832 + 62), dim3(256), 0, stream,
                       wfc, w_bin, w2, g2, v2, w2s, w1, g1, v1, w1ts, fmap_in, Anhwc,
                       boxes, rw);
    // wG[cb][o] = sum_cmid w_bin[cb][cmid] * w2s[o][cmid]   (M=256, N=1024, K=256)
    hipLaunchKernelGGL((k_gemm_sk<false>), dim3(64), dim3(512), 0, stream,
                       w_bin, w2s, wG, CIN_, CMID_, 64,
                       nullptr, nullptr, nullptr, nullptr, nullptr, nullptr,
                       nullptr, nullptr, nullptr, nullptr, nullptr, nullptr);
    // Wtot[cb][c] = sum_o wG[cb][o] * w1ts[c][o]  (64 blocks) + cfc (27 blocks)
    hipLaunchKernelGGL((k_gemm_sk<true>), dim3(64 + NCLS_), dim3(512), 0, stream,
                       wG, w1ts, Wtot, CIN_, CIN_, 64,
                       w_bin, wG, g1, b1, m1, v1, g2, b2, m2, v2, bfc, cfc);
    // G16[m][cb] = sum_c Anhwc[m][c] * Wtot[cb][c]          (M=3136, N=256, K=1024)
    hipLaunchKernelGGL((k_gemm_sk<false>), dim3(4 * 49), dim3(512), 0, stream,
                       Anhwc, Wtot, G16, NCB_, CIN_, 196,
                       nullptr, nullptr, nullptr, nullptr, nullptr, nullptr,
                       nullptr, nullptr, nullptr, nullptr, nullptr, nullptr);
    hipLaunchKernelGGL(k_roi_logits, dim3(NROI_ / 4), dim3(256), 0, stream,
                       rw, G16, cfc, (float*)d_out);
}